// Round 13
// baseline (162.487 us; speedup 1.0000x reference)
//
#include <hip/hip_runtime.h>
#include <hip/hip_bf16.h>
#include <cmath>

#define D_MODEL 128
#define NUM_HEAD 4
#define HEAD_DIM 32
#define SEQ 4096
#define BATCH 2
#define RROWS 8     // token rows per out_proj block
#define QROWS 16    // token rows per qkv block

typedef __attribute__((ext_vector_type(8))) short short8;
typedef __attribute__((ext_vector_type(4))) float f32x4;

__device__ __forceinline__ float tof(float x) { return x; }
__device__ __forceinline__ float tof(__hip_bfloat16 x) { return __bfloat162float(x); }
__device__ __forceinline__ void storef(float* p, size_t i, float v) { p[i] = v; }
__device__ __forceinline__ void storef(__hip_bfloat16* p, size_t i, float v) { p[i] = __float2bfloat16(v); }

// manual RNE split: x = hi + lo in bf16, error ~2^-18 relative
__device__ __forceinline__ void split_bf16(float x, unsigned short& hi, unsigned short& lo)
{
    const unsigned u = __float_as_uint(x);
    const unsigned r = u + 0x7FFFu + ((u >> 16) & 1u);
    hi = (unsigned short)(r >> 16);
    const float hf = __uint_as_float((unsigned)hi << 16);
    const float lf = x - hf;
    const unsigned ul = __float_as_uint(lf);
    const unsigned rl = ul + 0x7FFFu + ((ul >> 16) & 1u);
    lo = (unsigned short)(rl >> 16);
}
// hi-only RNE round (for P, whose lo term is dropped in PV)
__device__ __forceinline__ unsigned short rne_bf16(float x)
{
    const unsigned u = __float_as_uint(x);
    return (unsigned short)((u + 0x7FFFu + ((u >> 16) & 1u)) >> 16);
}

// async global->LDS, 16B per lane; dest is wave-uniform base + lane*16
__device__ __forceinline__ void g2l16(const void* g, void* l)
{
    __builtin_amdgcn_global_load_lds(
        (const __attribute__((address_space(1))) void*)g,
        (__attribute__((address_space(3))) void*)l, 16, 0, 0);
}

// ---------------------------------------------------------------------------
// Kernel 0 (R27): fused prep (unchanged).
// ---------------------------------------------------------------------------
__global__ __launch_bounds__(256) void prep_kernel(
    const void* wq, const void* wk, const void* wv, const void* wo,
    float* __restrict__ wt4, float* __restrict__ pe, int* __restrict__ flagp)
{
    const int bx  = blockIdx.x;
    const int tid = threadIdx.x;
    __shared__ int sflag;

    if (bx < 64) {
        {
            int weird = 0;
            if (tid < 64) {
                const unsigned short* w16 = (const unsigned short*)wq;
#pragma unroll
                for (int j = 0; j < 4; ++j) {
                    const unsigned short v = w16[(tid * 4 + j) * 2 + 1];
                    const float x = __uint_as_float((unsigned)v << 16);
                    const float a = fabsf(x);
                    if (a > 1e20f || (a > 0.f && a < 1e-20f)) weird++;
                }
#pragma unroll
                for (int off = 32; off; off >>= 1) weird += __shfl_xor(weird, off);
                if (tid == 0) sflag = (weird < 32) ? 1 : 0;
            }
            __syncthreads();
        }
        const int flag = sflag;
        if (bx == 0 && tid == 0) *flagp = flag;

        const int m = bx >> 4;                        // matrix 0..3
        const void* w = (m == 0) ? wq : (m == 1) ? wk : (m == 2) ? wv : wo;
        const int item = (bx & 15) * 256 + tid;       // 0..4095 float4-items
        const int e  = item & 127;
        const int dq = item >> 7;                     // 0..31
        float4 v;
        if (flag) {
            v = *(const float4*)((const float*)w + (size_t)e * 128 + dq * 4);
        } else {
            const __hip_bfloat16* wb = (const __hip_bfloat16*)w + (size_t)e * 128 + dq * 4;
            v = make_float4(tof(wb[0]), tof(wb[1]), tof(wb[2]), tof(wb[3]));
        }
        *(float4*)&wt4[(((size_t)m * 32 + dq) * 128 + e) * 4] = v;   // coalesced
    } else {
        // PE: idx 0..2047 -> i = idx&63 (freq), chunk = idx>>6 (128 s-rows)
        const int idx   = (bx - 64) * 256 + tid;
        const int i     = idx & 63;
        const int chunk = idx >> 6;
        const int s0    = chunk * 128;
        const double inv = 1.0 / pow(10000.0, (double)i / 64.0);
        const double a0  = (double)s0 * inv;
        double c  = cos(a0), s = sin(a0);
        const double cd = cos(inv), sd = sin(inv);
        float2* row = (float2*)&pe[(size_t)s0 * 128 + i * 2];
        for (int k = 0; k < 128; ++k) {
            float2 sc;
            sc.x = (float)s;
            sc.y = (float)c;
            row[(size_t)k * 64] = sc;                 // 8B/lane, wave-coalesced (i=lane)
            const double cn = c * cd - s * sd;
            s = s * cd + c * sd;
            c = cn;
        }
    }
}

// ---------------------------------------------------------------------------
// Kernel 1 (R28): qkv with d-SPLIT weight reads.
//   grp g reads only dq in [8g,8g+8) for ALL 16 rows (48 partial
//   accumulators), then a 2-barrier LDS reduction per matrix recombines in
//   ascending-g order (contiguous-d summation preserved; grouping change
//   last-ulp only). Weight traffic /4 (805MB -> 201MB); xs reads become
//   wave-broadcast (lane-invariant address -> conflict-free). Output
//   ownership after reduction matches the old mapping (rows grp*4..+3).
// ---------------------------------------------------------------------------
template <typename T>
__device__ __forceinline__ void qkv_body(
    const int* __restrict__ seq, const T* __restrict__ emb,
    const float* __restrict__ wt4, const float* __restrict__ pe,
    unsigned short* __restrict__ Qhi, unsigned short* __restrict__ Qlo,
    unsigned short* __restrict__ Khi, unsigned short* __restrict__ Klo,
    unsigned short* __restrict__ Vthi, unsigned short* __restrict__ Vtlo)
{
    const int tid = threadIdx.x;
    const int e   = tid & 127;
    const int grp = tid >> 7;                 // 0..3 = dq quarter AND row-group owner
    const int r0  = blockIdx.x * QROWS;

    __shared__ __align__(16) float xs[QROWS][D_MODEL];                // 8 KB
    __shared__ __align__(16) unsigned short vsh[2][QROWS][D_MODEL];   // 8 KB
    __shared__ __align__(16) float red[4][QROWS][D_MODEL];            // 32 KB (reused x3)

#pragma unroll
    for (int k = 0; k < 4; ++k) {
        const int idx = k * 512 + tid;        // 0..2047
        const int r  = idx >> 7;
        const int ee = idx & 127;
        const int srow = r0 + r;
        xs[r][ee] = tof(emb[(size_t)seq[srow] * D_MODEL + ee])
                  + pe[(size_t)(srow & (SEQ - 1)) * D_MODEL + ee];
    }
    __syncthreads();

    float aq[QROWS], ak[QROWS], av[QROWS];
#pragma unroll
    for (int r = 0; r < QROWS; ++r) { aq[r] = 0.f; ak[r] = 0.f; av[r] = 0.f; }

    const float4* wq4 = (const float4*)wt4;          // matrix stride = 4096 float4
    const float4* wk4 = wq4 + 4096;
    const float4* wv4 = wq4 + 8192;

    const int dqb = grp * 8;
    for (int j = 0; j < 8; ++j) {
        const int dq = dqb + j;
        const float4 wq_ = wq4[dq * 128 + e];        // coalesced, 1x traffic
        const float4 wk_ = wk4[dq * 128 + e];
        const float4 wv_ = wv4[dq * 128 + e];
#pragma unroll
        for (int r = 0; r < QROWS; ++r) {
            const float4 x = *(const float4*)&xs[r][dq * 4];   // wave-broadcast
            aq[r] += x.x * wq_.x; aq[r] += x.y * wq_.y;
            aq[r] += x.z * wq_.z; aq[r] += x.w * wq_.w;
            ak[r] += x.x * wk_.x; ak[r] += x.y * wk_.y;
            ak[r] += x.z * wk_.z; ak[r] += x.w * wk_.w;
            av[r] += x.x * wv_.x; av[r] += x.y * wv_.y;
            av[r] += x.z * wv_.z; av[r] += x.w * wv_.w;
        }
    }

    const int rbase = grp * 4;
    const float scale = 0.17677669529663687f;   // 1/sqrt(32) folded into Q

    // ---- reduce + emit Q ----
    __syncthreads();                             // red free (xs no longer written)
#pragma unroll
    for (int r = 0; r < QROWS; ++r) red[grp][r][e] = aq[r];
    __syncthreads();
#pragma unroll
    for (int r = 0; r < 4; ++r) {
        const int row = rbase + r;
        const float v = ((red[0][row][e] + red[1][row][e]) + red[2][row][e]) + red[3][row][e];
        const size_t o = (size_t)(r0 + row) * D_MODEL + e;
        unsigned short hi, lo;
        split_bf16(v * scale, hi, lo); Qhi[o] = hi; Qlo[o] = lo;
    }
    // ---- reduce + emit K ----
    __syncthreads();
#pragma unroll
    for (int r = 0; r < QROWS; ++r) red[grp][r][e] = ak[r];
    __syncthreads();
#pragma unroll
    for (int r = 0; r < 4; ++r) {
        const int row = rbase + r;
        const float v = ((red[0][row][e] + red[1][row][e]) + red[2][row][e]) + red[3][row][e];
        const size_t o = (size_t)(r0 + row) * D_MODEL + e;
        unsigned short hi, lo;
        split_bf16(v, hi, lo); Khi[o] = hi; Klo[o] = lo;
    }
    // ---- reduce + emit V (to vsh) ----
    __syncthreads();
#pragma unroll
    for (int r = 0; r < QROWS; ++r) red[grp][r][e] = av[r];
    __syncthreads();
#pragma unroll
    for (int r = 0; r < 4; ++r) {
        const int row = rbase + r;
        const float v = ((red[0][row][e] + red[1][row][e]) + red[2][row][e]) + red[3][row][e];
        unsigned short hi, lo;
        split_bf16(v, hi, lo);
        vsh[0][row][e] = hi; vsh[1][row][e] = lo;
    }
    __syncthreads();

    // coalesced V^T store (unchanged)
    {
        const int b  = r0 >> 12;
        const int s0 = r0 & (SEQ - 1);
        const int h  = s0 >> 10;
        const size_t vtb = (size_t)(b * 4 + h) * (32 * SEQ);
        const int hl = tid >> 8;             // 0..1 (hi/lo plane)
        const int d  = (tid >> 3) & 31;      // head-dim
        const int j  = tid & 7;              // k-octet within 64
        short8 tmp;
#pragma unroll
        for (int i = 0; i < 8; ++i) {
            const int kl = j * 8 + i;        // 0..63
            tmp[i] = (short)vsh[hl][kl >> 2][(kl & 3) * 32 + d];
        }
        unsigned short* dst = (hl ? Vtlo : Vthi) + vtb + (size_t)d * SEQ
                            + (size_t)(s0 & 1023) * 4 + j * 8;
        *(short8*)dst = tmp;
    }
}

__global__ __launch_bounds__(512, 2) void qkv_kernel(
    const int* __restrict__ seq, const void* emb,
    const float* __restrict__ wt4, const float* __restrict__ pe,
    unsigned short* Qhi, unsigned short* Qlo,
    unsigned short* Khi, unsigned short* Klo,
    unsigned short* Vthi, unsigned short* Vtlo,
    const int* __restrict__ flag)
{
    if (*flag)
        qkv_body<float>(seq, (const float*)emb, wt4, pe,
                        Qhi, Qlo, Khi, Klo, Vthi, Vtlo);
    else
        qkv_body<__hip_bfloat16>(seq, (const __hip_bfloat16*)emb, wt4, pe,
                                 Qhi, Qlo, Khi, Klo, Vthi, Vtlo);
}

// ---------------------------------------------------------------------------
// Kernel 2 (R27): flash attention, LDS-staged partial-sum form, 3-buffer
// rotation, one barrier per chunk. UNCHANGED (verified 57.9us).
// ---------------------------------------------------------------------------
__global__ __launch_bounds__(256, 4) void attn_kernel(
    const unsigned short* __restrict__ Qhi, const unsigned short* __restrict__ Qlo,
    const unsigned short* __restrict__ Khi, const unsigned short* __restrict__ Klo,
    const unsigned short* __restrict__ Vthi, const unsigned short* __restrict__ Vtlo,
    float* __restrict__ Apart, float* __restrict__ lbuf)
{
    const int bh   = blockIdx.x;
    const int by   = blockIdx.y;                  // 0..63
    const int kh   = blockIdx.z;                  // 0..3
    const int qt   = (by < 32) ? by : 95 - by;    // complementary pairing per CU
    const size_t baseQ  = (size_t)(bh >> 2) * SEQ * D_MODEL + (size_t)(bh & 3) * SEQ * HEAD_DIM;
    const size_t baseVt = (size_t)bh * (32 * SEQ);

    const int tid  = threadIdx.x;
    const int wid  = __builtin_amdgcn_readfirstlane(tid >> 6);
    const int lane = tid & 63;
    const int rt   = wid;                         // 0..3
    const int quad = lane >> 4;
    const int col  = lane & 15;

    __shared__ float shbuf[4 * 576];
    __shared__ __align__(16) unsigned char kv[3][8192];   // [buf][plane(4) x 2KB]
    float* pb = &shbuf[wid * 576];

    const int qrow0 = qt * 64 + rt * 16;

    short8 qhiF, qloF;
    {
        const size_t qo = baseQ + (size_t)(qrow0 + col) * HEAD_DIM + quad * 8;
        qhiF = *(const short8*)(Qhi + qo);
        qloF = *(const short8*)(Qlo + qo);
    }

    f32x4 O0 = {0.f, 0.f, 0.f, 0.f};
    f32x4 O1 = {0.f, 0.f, 0.f, 0.f};
    float l[4] = {0.f, 0.f, 0.f, 0.f};

    const int N   = 2 * (qt + 1);
    const int nb  = N >> 2, rem = N & 3;
    const int cnt  = nb + ((kh < rem) ? 1 : 0);
    const int cbeg = kh * nb + ((kh < rem) ? kh : rem);

    // stage one chunk's plane for this wave: 2 x (16B/lane) async copies
    const int r4 = lane >> 2, sseg = lane & 3;
    auto stage = [&](int bufi, int kbase) {
#pragma unroll
        for (int half = 0; half < 2; ++half) {
            const int row = half * 16 + r4;
            const int seg = sseg ^ (row & 3);     // pre-swizzled source (rule #21)
            const unsigned short* src;
            if (wid == 0)      src = Khi  + baseQ  + (size_t)(kbase + row) * HEAD_DIM + seg * 8;
            else if (wid == 1) src = Klo  + baseQ  + (size_t)(kbase + row) * HEAD_DIM + seg * 8;
            else if (wid == 2) src = Vthi + baseVt + (size_t)row * SEQ + kbase + seg * 8;
            else               src = Vtlo + baseVt + (size_t)row * SEQ + kbase + seg * 8;
            g2l16(src, &kv[bufi][wid * 2048 + half * 1024]);
        }
    };
    // swizzled fragment read: plane 0..3, row 0..31, quad 0..3 (16B)
    auto frag = [&](int bufi, int plane, int row) -> short8 {
        const int byte = plane * 2048 + row * 64 + ((quad ^ (row & 3)) << 4);
        return *(const short8*)(&kv[bufi][byte]);
    };

    if (cnt > 0) {
        stage(0, cbeg * 32);
        if (cnt > 1) stage(1, (cbeg + 1) * 32);
        int cur = 0;
        for (int i = 0; i < cnt; ++i) {
            const int c = cbeg + i;
            const int kbase = c * 32;
            if (i + 1 < cnt) { asm volatile("s_waitcnt vmcnt(2)" ::: "memory"); }
            else             { asm volatile("s_waitcnt vmcnt(0)" ::: "memory"); }
            __builtin_amdgcn_s_barrier();         // all 4 planes of buf[cur] ready
            __builtin_amdgcn_sched_barrier(0);    // pin restage below the barrier
            if (i + 2 < cnt) {
                int nx = cur + 2; if (nx > 2) nx -= 3;
                stage(nx, (c + 2) * 32);          // (i+2)%3 == (i-1)%3: safe post-barrier
            }

            const short8 k0h = frag(cur, 0, col);
            const short8 k0l = frag(cur, 1, col);
            const short8 k1h = frag(cur, 0, col + 16);
            const short8 k1l = frag(cur, 1, col + 16);

            f32x4 s0v = {0.f, 0.f, 0.f, 0.f};
            f32x4 s1v = {0.f, 0.f, 0.f, 0.f};
            s0v = __builtin_amdgcn_mfma_f32_16x16x32_bf16(qhiF, k0h, s0v, 0, 0, 0);
            s0v = __builtin_amdgcn_mfma_f32_16x16x32_bf16(qhiF, k0l, s0v, 0, 0, 0);
            s0v = __builtin_amdgcn_mfma_f32_16x16x32_bf16(qloF, k0h, s0v, 0, 0, 0);
            s1v = __builtin_amdgcn_mfma_f32_16x16x32_bf16(qhiF, k1h, s1v, 0, 0, 0);
            s1v = __builtin_amdgcn_mfma_f32_16x16x32_bf16(qhiF, k1l, s1v, 0, 0, 0);
            s1v = __builtin_amdgcn_mfma_f32_16x16x32_bf16(qloF, k1h, s1v, 0, 0, 0);

            // fixed m=0 softmax numerator: e = exp(|s|) where unmasked, else 0
#pragma unroll
            for (int r = 0; r < 4; ++r) {
                const int rowg = qrow0 + quad * 4 + r;
                const float e0 = (kbase + col      <= rowg) ? __expf(fabsf(s0v[r])) : 0.f;
                const float e1 = (kbase + 16 + col <= rowg) ? __expf(fabsf(s1v[r])) : 0.f;
                l[r] += e0 + e1;
                pb[(quad * 4 + r) * 36 + col]      = e0;
                pb[(quad * 4 + r) * 36 + 16 + col] = e1;
            }
            short8 ph;
            {
                const float4 p01 = *(const float4*)&pb[col * 36 + quad * 8];
                const float4 p23 = *(const float4*)&pb[col * 36 + quad * 8 + 4];
                ph[0] = (short)rne_bf16(p01.x); ph[1] = (short)rne_bf16(p01.y);
                ph[2] = (short)rne_bf16(p01.z); ph[3] = (short)rne_bf16(p01.w);
                ph[4] = (short)rne_bf16(p23.x); ph[5] = (short)rne_bf16(p23.y);
                ph[6] = (short)rne_bf16(p23.z); ph[7] = (short)rne_bf16(p23.w);
            }

            const short8 v0h = frag(cur, 2, col);
            const short8 v0l = frag(cur, 3, col);
            const short8 v1h = frag(cur, 2, col + 16);
            const short8 v1l = frag(cur, 3, col + 16);

            O0 = __builtin_amdgcn_mfma_f32_16x16x32_bf16(ph, v0h, O0, 0, 0, 0);
            O0 = __builtin_amdgcn_mfma_f32_16x16x32_bf16(ph, v0l, O0, 0, 0, 0);
            O1 = __builtin_amdgcn_mfma_f32_16x16x32_bf16(ph, v1h, O1, 0, 0, 0);
            O1 = __builtin_amdgcn_mfma_f32_16x16x32_bf16(ph, v1l, O1, 0, 0, 0);

            cur = (cur == 2) ? 0 : cur + 1;
        }
    }

    // row-sum of l across the 16 cols
#pragma unroll
    for (int off = 1; off < 16; off <<= 1) {
#pragma unroll
        for (int r = 0; r < 4; ++r) l[r] += __shfl_xor(l[r], off, 64);
    }

    // direct partial writes -- no cross-wave combine
    float* Ap = Apart + (size_t)kh * (BATCH * SEQ * D_MODEL) + baseQ;
#pragma unroll
    for (int r = 0; r < 4; ++r) {
        const int row = qrow0 + quad * 4 + r;
        Ap[(size_t)row * HEAD_DIM + col]      = O0[r];
        Ap[(size_t)row * HEAD_DIM + 16 + col] = O1[r];
    }
    if (col == 0) {
        float* lp = lbuf + ((size_t)kh * (BATCH * NUM_HEAD) + bh) * SEQ;
#pragma unroll
        for (int r = 0; r < 4; ++r)
            lp[qrow0 + quad * 4 + r] = l[r];
    }
}

// ---------------------------------------------------------------------------
// Kernel 3: out = att @ Wo^T, 4-way kh partial sum + 1/L folded in (unchanged)
// ---------------------------------------------------------------------------
template <typename T>
__device__ __forceinline__ void out_proj_body(
    const float* __restrict__ Apart, const float* __restrict__ lbuf,
    const float* __restrict__ wo4t, T* __restrict__ out)
{
    const int tid = threadIdx.x;
    const int e   = tid & 127;
    const int grp = tid >> 7;                 // 0..1 -> rows grp*4 .. grp*4+3
    const int r0  = blockIdx.x * RROWS;

    __shared__ __align__(16) float xs[RROWS][D_MODEL];
#pragma unroll
    for (int k = 0; k < 4; ++k) {
        const int idx = k * 256 + tid;        // 0..1023
        const int rr = idx >> 7;
        const int ee = idx & 127;
        const int gr = r0 + rr;               // global token row
        const int b  = gr >> 12;
        const int s  = gr & (SEQ - 1);
        const int bh = b * 4 + (s >> 10);
        const int hr = ((s & 1023) << 2) + (ee >> 5);   // head-row
        const size_t ai = (size_t)gr * D_MODEL + ee;
        float sum = 0.f, Ls = 0.f;
#pragma unroll
        for (int kh = 0; kh < 4; ++kh) {
            sum += Apart[(size_t)kh * (BATCH * SEQ * D_MODEL) + ai];
            Ls  += lbuf[((size_t)kh * (BATCH * NUM_HEAD) + bh) * SEQ + hr];
        }
        xs[rr][ee] = sum * (1.f / Ls);
    }
    __syncthreads();

    float acc[4] = {0.f, 0.f, 0.f, 0.f};
    const int rbase = grp * 4;
    const float4* w4 = (const float4*)wo4t;

    for (int dq = 0; dq < 32; ++dq) {
        float4 xr[4];
#pragma unroll
        for (int r = 0; r < 4; ++r) xr[r] = *(const float4*)&xs[rbase + r][dq * 4];
        const float4 w_ = w4[dq * 128 + e];
#pragma unroll
        for (int r = 0; r < 4; ++r) {
            acc[r] += xr[r].x * w_.x; acc[r] += xr[r].y * w_.y;
            acc[r] += xr[r].z * w_.z; acc[r] += xr[r].w * w_.w;
        }
    }
#pragma unroll
    for (int r = 0; r < 4; ++r)
        storef(out, (size_t)(r0 + rbase + r) * D_MODEL + e, acc[r]);
}

__global__ __launch_bounds__(256, 4) void out_proj_kernel(
    const float* __restrict__ Apart, const float* __restrict__ lbuf,
    const float* __restrict__ wo4t, void* out,
    const int* __restrict__ flag)
{
    if (*flag)
        out_proj_body<float>(Apart, lbuf, wo4t, (float*)out);
    else
        out_proj_body<__hip_bfloat16>(Apart, lbuf, wo4t, (__hip_bfloat16*)out);
}

extern "C" void kernel_launch(void* const* d_in, const int* in_sizes, int n_in,
                              void* d_out, int out_size, void* d_ws, size_t ws_size,
                              hipStream_t stream) {
    const int* seq = (const int*)d_in[0];
    const void* emb = d_in[1];
    const void* wq  = d_in[2];
    const void* wk  = d_in[3];
    const void* wv  = d_in[4];
    const void* wo  = d_in[5];

    const size_t N = (size_t)BATCH * SEQ * D_MODEL;   // 1,048,576 elements
    int*            flag = (int*)d_ws;
    unsigned short* Qhi  = (unsigned short*)((char*)d_ws + 256);
    unsigned short* Qlo  = Qhi + N;
    unsigned short* Khi  = Qlo + N;
    unsigned short* Klo  = Khi + N;
    unsigned short* Vthi = Klo + N;
    unsigned short* Vtlo = Vthi + N;
    float*          Apart = (float*)(Vtlo + N);       // 4 x [B,S,128] f32 (16 MB)
    float*          lbuf  = Apart + 4 * N;            // 4 x 8 x 4096 f32 (512 KB)
    float*          wt4   = lbuf + 4 * BATCH * NUM_HEAD * SEQ;
    float*          pe    = wt4 + 65536;              // 4096 x 128 f32 PE table

    prep_kernel<<<dim3(64 + 8), dim3(256), 0, stream>>>(wq, wk, wv, wo, wt4, pe, flag);
    qkv_kernel<<<dim3(BATCH * SEQ / QROWS), dim3(512), 0, stream>>>(
        seq, emb, wt4, pe,
        Qhi, Qlo, Khi, Klo, Vthi, Vtlo, flag);
    attn_kernel<<<dim3(BATCH * NUM_HEAD, 64, 4), dim3(256), 0, stream>>>(
        Qhi, Qlo, Khi, Klo, Vthi, Vtlo, Apart, lbuf);
    out_proj_kernel<<<dim3(BATCH * SEQ / RROWS), dim3(256), 0, stream>>>(
        Apart, lbuf, wt4 + 49152, d_out, flag);
}

// Round 17
// 152.416 us; speedup vs baseline: 1.0661x; 1.0661x over previous
//
#include <hip/hip_runtime.h>
#include <hip/hip_bf16.h>
#include <cmath>

#define D_MODEL 128
#define NUM_HEAD 4
#define HEAD_DIM 32
#define SEQ 4096
#define BATCH 2
#define RROWS 8     // token rows per out_proj block
#define QROWS 16    // token rows per qkv block

typedef __attribute__((ext_vector_type(8))) short short8;
typedef __attribute__((ext_vector_type(4))) float f32x4;

__device__ __forceinline__ float tof(float x) { return x; }
__device__ __forceinline__ float tof(__hip_bfloat16 x) { return __bfloat162float(x); }
__device__ __forceinline__ void storef(float* p, size_t i, float v) { p[i] = v; }
__device__ __forceinline__ void storef(__hip_bfloat16* p, size_t i, float v) { p[i] = __float2bfloat16(v); }

// manual RNE split: x = hi + lo in bf16, error ~2^-18 relative
__device__ __forceinline__ void split_bf16(float x, unsigned short& hi, unsigned short& lo)
{
    const unsigned u = __float_as_uint(x);
    const unsigned r = u + 0x7FFFu + ((u >> 16) & 1u);
    hi = (unsigned short)(r >> 16);
    const float hf = __uint_as_float((unsigned)hi << 16);
    const float lf = x - hf;
    const unsigned ul = __float_as_uint(lf);
    const unsigned rl = ul + 0x7FFFu + ((ul >> 16) & 1u);
    lo = (unsigned short)(rl >> 16);
}
// hi-only RNE round (for P, whose lo term is dropped in PV)
__device__ __forceinline__ unsigned short rne_bf16(float x)
{
    const unsigned u = __float_as_uint(x);
    return (unsigned short)((u + 0x7FFFu + ((u >> 16) & 1u)) >> 16);
}

// async global->LDS, 16B per lane; dest is wave-uniform base + lane*16
__device__ __forceinline__ void g2l16(const void* g, void* l)
{
    __builtin_amdgcn_global_load_lds(
        (const __attribute__((address_space(1))) void*)g,
        (__attribute__((address_space(3))) void*)l, 16, 0, 0);
}

// ---------------------------------------------------------------------------
// Kernel 0 (R27): fused prep (unchanged, measured).
// ---------------------------------------------------------------------------
__global__ __launch_bounds__(256) void prep_kernel(
    const void* wq, const void* wk, const void* wv, const void* wo,
    float* __restrict__ wt4, float* __restrict__ pe, int* __restrict__ flagp)
{
    const int bx  = blockIdx.x;
    const int tid = threadIdx.x;
    __shared__ int sflag;

    if (bx < 64) {
        {
            int weird = 0;
            if (tid < 64) {
                const unsigned short* w16 = (const unsigned short*)wq;
#pragma unroll
                for (int j = 0; j < 4; ++j) {
                    const unsigned short v = w16[(tid * 4 + j) * 2 + 1];
                    const float x = __uint_as_float((unsigned)v << 16);
                    const float a = fabsf(x);
                    if (a > 1e20f || (a > 0.f && a < 1e-20f)) weird++;
                }
#pragma unroll
                for (int off = 32; off; off >>= 1) weird += __shfl_xor(weird, off);
                if (tid == 0) sflag = (weird < 32) ? 1 : 0;
            }
            __syncthreads();
        }
        const int flag = sflag;
        if (bx == 0 && tid == 0) *flagp = flag;

        const int m = bx >> 4;                        // matrix 0..3
        const void* w = (m == 0) ? wq : (m == 1) ? wk : (m == 2) ? wv : wo;
        const int item = (bx & 15) * 256 + tid;       // 0..4095 float4-items
        const int e  = item & 127;
        const int dq = item >> 7;                     // 0..31
        float4 v;
        if (flag) {
            v = *(const float4*)((const float*)w + (size_t)e * 128 + dq * 4);
        } else {
            const __hip_bfloat16* wb = (const __hip_bfloat16*)w + (size_t)e * 128 + dq * 4;
            v = make_float4(tof(wb[0]), tof(wb[1]), tof(wb[2]), tof(wb[3]));
        }
        *(float4*)&wt4[(((size_t)m * 32 + dq) * 128 + e) * 4] = v;   // coalesced
    } else {
        // PE: idx 0..2047 -> i = idx&63 (freq), chunk = idx>>6 (128 s-rows)
        const int idx   = (bx - 64) * 256 + tid;
        const int i     = idx & 63;
        const int chunk = idx >> 6;
        const int s0    = chunk * 128;
        const double inv = 1.0 / pow(10000.0, (double)i / 64.0);
        const double a0  = (double)s0 * inv;
        double c  = cos(a0), s = sin(a0);
        const double cd = cos(inv), sd = sin(inv);
        float2* row = (float2*)&pe[(size_t)s0 * 128 + i * 2];
        for (int k = 0; k < 128; ++k) {
            float2 sc;
            sc.x = (float)s;
            sc.y = (float)c;
            row[(size_t)k * 64] = sc;                 // 8B/lane, wave-coalesced (i=lane)
            const double cn = c * cd - s * sd;
            s = s * cd + c * sd;
            c = cn;
        }
    }
}

// ---------------------------------------------------------------------------
// Kernel 1: qkv (R26-measured form).
// ---------------------------------------------------------------------------
template <typename T>
__device__ __forceinline__ void qkv_body(
    const int* __restrict__ seq, const T* __restrict__ emb,
    const float* __restrict__ wt4, const float* __restrict__ pe,
    unsigned short* __restrict__ Qhi, unsigned short* __restrict__ Qlo,
    unsigned short* __restrict__ Khi, unsigned short* __restrict__ Klo,
    unsigned short* __restrict__ Vthi, unsigned short* __restrict__ Vtlo)
{
    const int tid = threadIdx.x;
    const int e   = tid & 127;
    const int grp = tid >> 7;                 // 0..3 -> rows grp*4 .. grp*4+3
    const int r0  = blockIdx.x * QROWS;

    __shared__ __align__(16) float xs[QROWS][D_MODEL];
    __shared__ __align__(16) unsigned short vsh[2][QROWS][D_MODEL];

#pragma unroll
    for (int k = 0; k < 4; ++k) {
        const int idx = k * 512 + tid;        // 0..2047
        const int r  = idx >> 7;
        const int ee = idx & 127;
        const int srow = r0 + r;
        xs[r][ee] = tof(emb[(size_t)seq[srow] * D_MODEL + ee])
                  + pe[(size_t)(srow & (SEQ - 1)) * D_MODEL + ee];
    }
    __syncthreads();

    float aq[4], ak[4], av[4];
#pragma unroll
    for (int r = 0; r < 4; ++r) { aq[r] = 0.f; ak[r] = 0.f; av[r] = 0.f; }

    const int rbase = grp * 4;
    const float4* wq4 = (const float4*)wt4;          // matrix stride = 4096 float4
    const float4* wk4 = wq4 + 4096;
    const float4* wv4 = wq4 + 8192;

    for (int dq = 0; dq < 32; ++dq) {
        float4 xr[4];
#pragma unroll
        for (int r = 0; r < 4; ++r) xr[r] = *(const float4*)&xs[rbase + r][dq * 4];
        const float4 wq_ = wq4[dq * 128 + e];
        const float4 wk_ = wk4[dq * 128 + e];
        const float4 wv_ = wv4[dq * 128 + e];
#pragma unroll
        for (int r = 0; r < 4; ++r) {
            aq[r] += xr[r].x * wq_.x; aq[r] += xr[r].y * wq_.y;
            aq[r] += xr[r].z * wq_.z; aq[r] += xr[r].w * wq_.w;
            ak[r] += xr[r].x * wk_.x; ak[r] += xr[r].y * wk_.y;
            ak[r] += xr[r].z * wk_.z; ak[r] += xr[r].w * wk_.w;
            av[r] += xr[r].x * wv_.x; av[r] += xr[r].y * wv_.y;
            av[r] += xr[r].z * wv_.z; av[r] += xr[r].w * wv_.w;
        }
    }

    const float scale = 0.17677669529663687f;   // 1/sqrt(32) folded into Q
#pragma unroll
    for (int r = 0; r < 4; ++r) {
        const int row = rbase + r;
        const size_t o = (size_t)(r0 + row) * D_MODEL + e;
        unsigned short hi, lo;
        split_bf16(aq[r] * scale, hi, lo); Qhi[o] = hi; Qlo[o] = lo;
        split_bf16(ak[r], hi, lo);         Khi[o] = hi; Klo[o] = lo;
        split_bf16(av[r], hi, lo);         vsh[0][row][e] = hi; vsh[1][row][e] = lo;
    }
    __syncthreads();

    // coalesced V^T store
    {
        const int b  = r0 >> 12;
        const int s0 = r0 & (SEQ - 1);
        const int h  = s0 >> 10;
        const size_t vtb = (size_t)(b * 4 + h) * (32 * SEQ);
        const int hl = tid >> 8;             // 0..1 (hi/lo plane)
        const int d  = (tid >> 3) & 31;      // head-dim
        const int j  = tid & 7;              // k-octet within 64
        short8 tmp;
#pragma unroll
        for (int i = 0; i < 8; ++i) {
            const int kl = j * 8 + i;        // 0..63
            tmp[i] = (short)vsh[hl][kl >> 2][(kl & 3) * 32 + d];
        }
        unsigned short* dst = (hl ? Vtlo : Vthi) + vtb + (size_t)d * SEQ
                            + (size_t)(s0 & 1023) * 4 + j * 8;
        *(short8*)dst = tmp;
    }
}

__global__ __launch_bounds__(512, 4) void qkv_kernel(
    const int* __restrict__ seq, const void* emb,
    const float* __restrict__ wt4, const float* __restrict__ pe,
    unsigned short* Qhi, unsigned short* Qlo,
    unsigned short* Khi, unsigned short* Klo,
    unsigned short* Vthi, unsigned short* Vtlo,
    const int* __restrict__ flag)
{
    if (*flag)
        qkv_body<float>(seq, (const float*)emb, wt4, pe,
                        Qhi, Qlo, Khi, Klo, Vthi, Vtlo);
    else
        qkv_body<__hip_bfloat16>(seq, (const __hip_bfloat16*)emb, wt4, pe,
                                 Qhi, Qlo, Khi, Klo, Vthi, Vtlo);
}

// ---------------------------------------------------------------------------
// Kernel 2 (R29): flash attention, LDS-staged partial-sum form + 3-buffer
// pipeline (R27, verified) + COMPLEMENTARY qt-PAIRING inside each block:
//   block (bh, pair, kh) computes qt=pair then qt=63-pair sequentially ->
//   every block does ~32-33 chunks (uniform), grid = 1024 blocks = exactly
//   4 blocks/CU (LDS limit) -> whole grid co-resident, uniform finish, no
//   heavy-block tail (R28 counters: Occupancy 26% from imbalance).
//   One s_barrier between the two halves protects kv from early restaging
//   (cnt is block-uniform so barrier convergence is safe).
// ---------------------------------------------------------------------------
__global__ __launch_bounds__(256, 4) void attn_kernel(
    const unsigned short* __restrict__ Qhi, const unsigned short* __restrict__ Qlo,
    const unsigned short* __restrict__ Khi, const unsigned short* __restrict__ Klo,
    const unsigned short* __restrict__ Vthi, const unsigned short* __restrict__ Vtlo,
    float* __restrict__ Apart, float* __restrict__ lbuf)
{
    const int bh   = blockIdx.x;
    const int pair = blockIdx.y;                  // 0..31
    const int kh   = blockIdx.z;                  // 0..3
    const size_t baseQ  = (size_t)(bh >> 2) * SEQ * D_MODEL + (size_t)(bh & 3) * SEQ * HEAD_DIM;
    const size_t baseVt = (size_t)bh * (32 * SEQ);

    const int tid  = threadIdx.x;
    const int wid  = __builtin_amdgcn_readfirstlane(tid >> 6);
    const int lane = tid & 63;
    const int rt   = wid;                         // 0..3
    const int quad = lane >> 4;
    const int col  = lane & 15;

    __shared__ float shbuf[4 * 576];
    __shared__ __align__(16) unsigned char kv[3][8192];   // [buf][plane(4) x 2KB]
    float* pb = &shbuf[wid * 576];

    // stage one chunk's plane for this wave: 2 x (16B/lane) async copies
    const int r4 = lane >> 2, sseg = lane & 3;
    auto stage = [&](int bufi, int kbase) {
#pragma unroll
        for (int half = 0; half < 2; ++half) {
            const int row = half * 16 + r4;
            const int seg = sseg ^ (row & 3);     // pre-swizzled source (rule #21)
            const unsigned short* src;
            if (wid == 0)      src = Khi  + baseQ  + (size_t)(kbase + row) * HEAD_DIM + seg * 8;
            else if (wid == 1) src = Klo  + baseQ  + (size_t)(kbase + row) * HEAD_DIM + seg * 8;
            else if (wid == 2) src = Vthi + baseVt + (size_t)row * SEQ + kbase + seg * 8;
            else               src = Vtlo + baseVt + (size_t)row * SEQ + kbase + seg * 8;
            g2l16(src, &kv[bufi][wid * 2048 + half * 1024]);
        }
    };
    // swizzled fragment read: plane 0..3, row 0..31, quad 0..3 (16B)
    auto frag = [&](int bufi, int plane, int row) -> short8 {
        const int byte = plane * 2048 + row * 64 + ((quad ^ (row & 3)) << 4);
        return *(const short8*)(&kv[bufi][byte]);
    };

#pragma unroll 1
    for (int ti = 0; ti < 2; ++ti) {
        const int qt = ti ? (63 - pair) : pair;
        const int qrow0 = qt * 64 + rt * 16;

        short8 qhiF, qloF;
        {
            const size_t qo = baseQ + (size_t)(qrow0 + col) * HEAD_DIM + quad * 8;
            qhiF = *(const short8*)(Qhi + qo);
            qloF = *(const short8*)(Qlo + qo);
        }

        f32x4 O0 = {0.f, 0.f, 0.f, 0.f};
        f32x4 O1 = {0.f, 0.f, 0.f, 0.f};
        float l[4] = {0.f, 0.f, 0.f, 0.f};

        const int N   = 2 * (qt + 1);
        const int nb  = N >> 2, rem = N & 3;
        const int cnt  = nb + ((kh < rem) ? 1 : 0);     // block-uniform
        const int cbeg = kh * nb + ((kh < rem) ? kh : rem);

        if (cnt > 0) {
            stage(0, cbeg * 32);
            if (cnt > 1) stage(1, (cbeg + 1) * 32);
            int cur = 0;
            for (int i = 0; i < cnt; ++i) {
                const int c = cbeg + i;
                const int kbase = c * 32;
                if (i + 1 < cnt) { asm volatile("s_waitcnt vmcnt(2)" ::: "memory"); }
                else             { asm volatile("s_waitcnt vmcnt(0)" ::: "memory"); }
                __builtin_amdgcn_s_barrier();         // all 4 planes of buf[cur] ready
                __builtin_amdgcn_sched_barrier(0);    // pin restage below the barrier
                if (i + 2 < cnt) {
                    int nx = cur + 2; if (nx > 2) nx -= 3;
                    stage(nx, (c + 2) * 32);          // (i+2)%3 == (i-1)%3: safe post-barrier
                }

                const short8 k0h = frag(cur, 0, col);
                const short8 k0l = frag(cur, 1, col);
                const short8 k1h = frag(cur, 0, col + 16);
                const short8 k1l = frag(cur, 1, col + 16);

                f32x4 s0v = {0.f, 0.f, 0.f, 0.f};
                f32x4 s1v = {0.f, 0.f, 0.f, 0.f};
                s0v = __builtin_amdgcn_mfma_f32_16x16x32_bf16(qhiF, k0h, s0v, 0, 0, 0);
                s0v = __builtin_amdgcn_mfma_f32_16x16x32_bf16(qhiF, k0l, s0v, 0, 0, 0);
                s0v = __builtin_amdgcn_mfma_f32_16x16x32_bf16(qloF, k0h, s0v, 0, 0, 0);
                s1v = __builtin_amdgcn_mfma_f32_16x16x32_bf16(qhiF, k1h, s1v, 0, 0, 0);
                s1v = __builtin_amdgcn_mfma_f32_16x16x32_bf16(qhiF, k1l, s1v, 0, 0, 0);
                s1v = __builtin_amdgcn_mfma_f32_16x16x32_bf16(qloF, k1h, s1v, 0, 0, 0);

                // fixed m=0 softmax numerator: e = exp(|s|) where unmasked, else 0
#pragma unroll
                for (int r = 0; r < 4; ++r) {
                    const int rowg = qrow0 + quad * 4 + r;
                    const float e0 = (kbase + col      <= rowg) ? __expf(fabsf(s0v[r])) : 0.f;
                    const float e1 = (kbase + 16 + col <= rowg) ? __expf(fabsf(s1v[r])) : 0.f;
                    l[r] += e0 + e1;
                    pb[(quad * 4 + r) * 36 + col]      = e0;
                    pb[(quad * 4 + r) * 36 + 16 + col] = e1;
                }
                short8 ph;
                {
                    const float4 p01 = *(const float4*)&pb[col * 36 + quad * 8];
                    const float4 p23 = *(const float4*)&pb[col * 36 + quad * 8 + 4];
                    ph[0] = (short)rne_bf16(p01.x); ph[1] = (short)rne_bf16(p01.y);
                    ph[2] = (short)rne_bf16(p01.z); ph[3] = (short)rne_bf16(p01.w);
                    ph[4] = (short)rne_bf16(p23.x); ph[5] = (short)rne_bf16(p23.y);
                    ph[6] = (short)rne_bf16(p23.z); ph[7] = (short)rne_bf16(p23.w);
                }

                const short8 v0h = frag(cur, 2, col);
                const short8 v0l = frag(cur, 3, col);
                const short8 v1h = frag(cur, 2, col + 16);
                const short8 v1l = frag(cur, 3, col + 16);

                O0 = __builtin_amdgcn_mfma_f32_16x16x32_bf16(ph, v0h, O0, 0, 0, 0);
                O0 = __builtin_amdgcn_mfma_f32_16x16x32_bf16(ph, v0l, O0, 0, 0, 0);
                O1 = __builtin_amdgcn_mfma_f32_16x16x32_bf16(ph, v1h, O1, 0, 0, 0);
                O1 = __builtin_amdgcn_mfma_f32_16x16x32_bf16(ph, v1l, O1, 0, 0, 0);

                cur = (cur == 2) ? 0 : cur + 1;
            }
        }

        // row-sum of l across the 16 cols
#pragma unroll
        for (int off = 1; off < 16; off <<= 1) {
#pragma unroll
            for (int r = 0; r < 4; ++r) l[r] += __shfl_xor(l[r], off, 64);
        }

        // direct partial writes -- no cross-wave combine
        float* Ap = Apart + (size_t)kh * (BATCH * SEQ * D_MODEL) + baseQ;
#pragma unroll
        for (int r = 0; r < 4; ++r) {
            const int row = qrow0 + quad * 4 + r;
            Ap[(size_t)row * HEAD_DIM + col]      = O0[r];
            Ap[(size_t)row * HEAD_DIM + 16 + col] = O1[r];
        }
        if (col == 0) {
            float* lp = lbuf + ((size_t)kh * (BATCH * NUM_HEAD) + bh) * SEQ;
#pragma unroll
            for (int r = 0; r < 4; ++r)
                lp[qrow0 + quad * 4 + r] = l[r];
        }

        __builtin_amdgcn_s_barrier();   // all waves done reading kv before next-ti restage
    }
}

// ---------------------------------------------------------------------------
// Kernel 3: out = att @ Wo^T, 4-way kh partial sum + 1/L folded in (unchanged)
// ---------------------------------------------------------------------------
template <typename T>
__device__ __forceinline__ void out_proj_body(
    const float* __restrict__ Apart, const float* __restrict__ lbuf,
    const float* __restrict__ wo4t, T* __restrict__ out)
{
    const int tid = threadIdx.x;
    const int e   = tid & 127;
    const int grp = tid >> 7;                 // 0..1 -> rows grp*4 .. grp*4+3
    const int r0  = blockIdx.x * RROWS;

    __shared__ __align__(16) float xs[RROWS][D_MODEL];
#pragma unroll
    for (int k = 0; k < 4; ++k) {
        const int idx = k * 256 + tid;        // 0..1023
        const int rr = idx >> 7;
        const int ee = idx & 127;
        const int gr = r0 + rr;               // global token row
        const int b  = gr >> 12;
        const int s  = gr & (SEQ - 1);
        const int bh = b * 4 + (s >> 10);
        const int hr = ((s & 1023) << 2) + (ee >> 5);   // head-row
        const size_t ai = (size_t)gr * D_MODEL + ee;
        float sum = 0.f, Ls = 0.f;
#pragma unroll
        for (int kh = 0; kh < 4; ++kh) {
            sum += Apart[(size_t)kh * (BATCH * SEQ * D_MODEL) + ai];
            Ls  += lbuf[((size_t)kh * (BATCH * NUM_HEAD) + bh) * SEQ + hr];
        }
        xs[rr][ee] = sum * (1.f / Ls);
    }
    __syncthreads();

    float acc[4] = {0.f, 0.f, 0.f, 0.f};
    const int rbase = grp * 4;
    const float4* w4 = (const float4*)wo4t;

    for (int dq = 0; dq < 32; ++dq) {
        float4 xr[4];
#pragma unroll
        for (int r = 0; r < 4; ++r) xr[r] = *(const float4*)&xs[rbase + r][dq * 4];
        const float4 w_ = w4[dq * 128 + e];
#pragma unroll
        for (int r = 0; r < 4; ++r) {
            acc[r] += xr[r].x * w_.x; acc[r] += xr[r].y * w_.y;
            acc[r] += xr[r].z * w_.z; acc[r] += xr[r].w * w_.w;
        }
    }
#pragma unroll
    for (int r = 0; r < 4; ++r)
        storef(out, (size_t)(r0 + rbase + r) * D_MODEL + e, acc[r]);
}

__global__ __launch_bounds__(256, 4) void out_proj_kernel(
    const float* __restrict__ Apart, const float* __restrict__ lbuf,
    const float* __restrict__ wo4t, void* out,
    const int* __restrict__ flag)
{
    if (*flag)
        out_proj_body<float>(Apart, lbuf, wo4t, (float*)out);
    else
        out_proj_body<__hip_bfloat16>(Apart, lbuf, wo4t, (__hip_bfloat16*)out);
}

extern "C" void kernel_launch(void* const* d_in, const int* in_sizes, int n_in,
                              void* d_out, int out_size, void* d_ws, size_t ws_size,
                              hipStream_t stream) {
    const int* seq = (const int*)d_in[0];
    const void* emb = d_in[1];
    const void* wq  = d_in[2];
    const void* wk  = d_in[3];
    const void* wv  = d_in[4];
    const void* wo  = d_in[5];

    const size_t N = (size_t)BATCH * SEQ * D_MODEL;   // 1,048,576 elements
    int*            flag = (int*)d_ws;
    unsigned short* Qhi  = (unsigned short*)((char*)d_ws + 256);
    unsigned short* Qlo  = Qhi + N;
    unsigned short* Khi  = Qlo + N;
    unsigned short* Klo  = Khi + N;
    unsigned short* Vthi = Klo + N;
    unsigned short* Vtlo = Vthi + N;
    float*          Apart = (float*)(Vtlo + N);       // 4 x [B,S,128] f32 (16 MB)
    float*          lbuf  = Apart + 4 * N;            // 4 x 8 x 4096 f32 (512 KB)
    float*          wt4   = lbuf + 4 * BATCH * NUM_HEAD * SEQ;
    float*          pe    = wt4 + 65536;              // 4096 x 128 f32 PE table

    prep_kernel<<<dim3(64 + 8), dim3(256), 0, stream>>>(wq, wk, wv, wo, wt4, pe, flag);
    qkv_kernel<<<dim3(BATCH * SEQ / QROWS), dim3(512), 0, stream>>>(
        seq, emb, wt4, pe,
        Qhi, Qlo, Khi, Klo, Vthi, Vtlo, flag);
    attn_kernel<<<dim3(BATCH * NUM_HEAD, 32, 4), dim3(256), 0, stream>>>(
        Qhi, Qlo, Khi, Klo, Vthi, Vtlo, Apart, lbuf);
    out_proj_kernel<<<dim3(BATCH * SEQ / RROWS), dim3(256), 0, stream>>>(
        Apart, lbuf, wt4 + 49152, d_out, flag);
}

// Round 20
// 151.280 us; speedup vs baseline: 1.0741x; 1.0075x over previous
//
#include <hip/hip_runtime.h>
#include <hip/hip_bf16.h>
#include <cmath>

#define D_MODEL 128
#define NUM_HEAD 4
#define HEAD_DIM 32
#define SEQ 4096
#define BATCH 2
#define RROWS 8     // token rows per out_proj block
#define QROWS 16    // token rows per qkv block

typedef __attribute__((ext_vector_type(8))) short short8;
typedef __attribute__((ext_vector_type(4))) float f32x4;

__device__ __forceinline__ float tof(float x) { return x; }
__device__ __forceinline__ float tof(__hip_bfloat16 x) { return __bfloat162float(x); }
__device__ __forceinline__ void storef(float* p, size_t i, float v) { p[i] = v; }
__device__ __forceinline__ void storef(__hip_bfloat16* p, size_t i, float v) { p[i] = __float2bfloat16(v); }

// manual RNE split: x = hi + lo in bf16, error ~2^-18 relative
__device__ __forceinline__ void split_bf16(float x, unsigned short& hi, unsigned short& lo)
{
    const unsigned u = __float_as_uint(x);
    const unsigned r = u + 0x7FFFu + ((u >> 16) & 1u);
    hi = (unsigned short)(r >> 16);
    const float hf = __uint_as_float((unsigned)hi << 16);
    const float lf = x - hf;
    const unsigned ul = __float_as_uint(lf);
    const unsigned rl = ul + 0x7FFFu + ((ul >> 16) & 1u);
    lo = (unsigned short)(rl >> 16);
}
// hi-only RNE round (for P, whose lo term is dropped in PV)
__device__ __forceinline__ unsigned short rne_bf16(float x)
{
    const unsigned u = __float_as_uint(x);
    return (unsigned short)((u + 0x7FFFu + ((u >> 16) & 1u)) >> 16);
}

// async global->LDS, 16B per lane; dest is wave-uniform base + lane*16
__device__ __forceinline__ void g2l16(const void* g, void* l)
{
    __builtin_amdgcn_global_load_lds(
        (const __attribute__((address_space(1))) void*)g,
        (__attribute__((address_space(3))) void*)l, 16, 0, 0);
}

// ---------------------------------------------------------------------------
// Kernel 0 (R27): fused prep (unchanged, measured).
// ---------------------------------------------------------------------------
__global__ __launch_bounds__(256) void prep_kernel(
    const void* wq, const void* wk, const void* wv, const void* wo,
    float* __restrict__ wt4, float* __restrict__ pe, int* __restrict__ flagp)
{
    const int bx  = blockIdx.x;
    const int tid = threadIdx.x;
    __shared__ int sflag;

    if (bx < 64) {
        {
            int weird = 0;
            if (tid < 64) {
                const unsigned short* w16 = (const unsigned short*)wq;
#pragma unroll
                for (int j = 0; j < 4; ++j) {
                    const unsigned short v = w16[(tid * 4 + j) * 2 + 1];
                    const float x = __uint_as_float((unsigned)v << 16);
                    const float a = fabsf(x);
                    if (a > 1e20f || (a > 0.f && a < 1e-20f)) weird++;
                }
#pragma unroll
                for (int off = 32; off; off >>= 1) weird += __shfl_xor(weird, off);
                if (tid == 0) sflag = (weird < 32) ? 1 : 0;
            }
            __syncthreads();
        }
        const int flag = sflag;
        if (bx == 0 && tid == 0) *flagp = flag;

        const int m = bx >> 4;                        // matrix 0..3
        const void* w = (m == 0) ? wq : (m == 1) ? wk : (m == 2) ? wv : wo;
        const int item = (bx & 15) * 256 + tid;       // 0..4095 float4-items
        const int e  = item & 127;
        const int dq = item >> 7;                     // 0..31
        float4 v;
        if (flag) {
            v = *(const float4*)((const float*)w + (size_t)e * 128 + dq * 4);
        } else {
            const __hip_bfloat16* wb = (const __hip_bfloat16*)w + (size_t)e * 128 + dq * 4;
            v = make_float4(tof(wb[0]), tof(wb[1]), tof(wb[2]), tof(wb[3]));
        }
        *(float4*)&wt4[(((size_t)m * 32 + dq) * 128 + e) * 4] = v;   // coalesced
    } else {
        // PE: idx 0..2047 -> i = idx&63 (freq), chunk = idx>>6 (128 s-rows)
        const int idx   = (bx - 64) * 256 + tid;
        const int i     = idx & 63;
        const int chunk = idx >> 6;
        const int s0    = chunk * 128;
        const double inv = 1.0 / pow(10000.0, (double)i / 64.0);
        const double a0  = (double)s0 * inv;
        double c  = cos(a0), s = sin(a0);
        const double cd = cos(inv), sd = sin(inv);
        float2* row = (float2*)&pe[(size_t)s0 * 128 + i * 2];
        for (int k = 0; k < 128; ++k) {
            float2 sc;
            sc.x = (float)s;
            sc.y = (float)c;
            row[(size_t)k * 64] = sc;                 // 8B/lane, wave-coalesced (i=lane)
            const double cn = c * cd - s * sd;
            s = s * cd + c * sd;
            c = cn;
        }
    }
}

// ---------------------------------------------------------------------------
// Kernel 1: qkv (R26-measured form, unchanged).
// ---------------------------------------------------------------------------
template <typename T>
__device__ __forceinline__ void qkv_body(
    const int* __restrict__ seq, const T* __restrict__ emb,
    const float* __restrict__ wt4, const float* __restrict__ pe,
    unsigned short* __restrict__ Qhi, unsigned short* __restrict__ Qlo,
    unsigned short* __restrict__ Khi, unsigned short* __restrict__ Klo,
    unsigned short* __restrict__ Vthi, unsigned short* __restrict__ Vtlo)
{
    const int tid = threadIdx.x;
    const int e   = tid & 127;
    const int grp = tid >> 7;                 // 0..3 -> rows grp*4 .. grp*4+3
    const int r0  = blockIdx.x * QROWS;

    __shared__ __align__(16) float xs[QROWS][D_MODEL];
    __shared__ __align__(16) unsigned short vsh[2][QROWS][D_MODEL];

#pragma unroll
    for (int k = 0; k < 4; ++k) {
        const int idx = k * 512 + tid;        // 0..2047
        const int r  = idx >> 7;
        const int ee = idx & 127;
        const int srow = r0 + r;
        xs[r][ee] = tof(emb[(size_t)seq[srow] * D_MODEL + ee])
                  + pe[(size_t)(srow & (SEQ - 1)) * D_MODEL + ee];
    }
    __syncthreads();

    float aq[4], ak[4], av[4];
#pragma unroll
    for (int r = 0; r < 4; ++r) { aq[r] = 0.f; ak[r] = 0.f; av[r] = 0.f; }

    const int rbase = grp * 4;
    const float4* wq4 = (const float4*)wt4;          // matrix stride = 4096 float4
    const float4* wk4 = wq4 + 4096;
    const float4* wv4 = wq4 + 8192;

    for (int dq = 0; dq < 32; ++dq) {
        float4 xr[4];
#pragma unroll
        for (int r = 0; r < 4; ++r) xr[r] = *(const float4*)&xs[rbase + r][dq * 4];
        const float4 wq_ = wq4[dq * 128 + e];
        const float4 wk_ = wk4[dq * 128 + e];
        const float4 wv_ = wv4[dq * 128 + e];
#pragma unroll
        for (int r = 0; r < 4; ++r) {
            aq[r] += xr[r].x * wq_.x; aq[r] += xr[r].y * wq_.y;
            aq[r] += xr[r].z * wq_.z; aq[r] += xr[r].w * wq_.w;
            ak[r] += xr[r].x * wk_.x; ak[r] += xr[r].y * wk_.y;
            ak[r] += xr[r].z * wk_.z; ak[r] += xr[r].w * wk_.w;
            av[r] += xr[r].x * wv_.x; av[r] += xr[r].y * wv_.y;
            av[r] += xr[r].z * wv_.z; av[r] += xr[r].w * wv_.w;
        }
    }

    const float scale = 0.17677669529663687f;   // 1/sqrt(32) folded into Q
#pragma unroll
    for (int r = 0; r < 4; ++r) {
        const int row = rbase + r;
        const size_t o = (size_t)(r0 + row) * D_MODEL + e;
        unsigned short hi, lo;
        split_bf16(aq[r] * scale, hi, lo); Qhi[o] = hi; Qlo[o] = lo;
        split_bf16(ak[r], hi, lo);         Khi[o] = hi; Klo[o] = lo;
        split_bf16(av[r], hi, lo);         vsh[0][row][e] = hi; vsh[1][row][e] = lo;
    }
    __syncthreads();

    // coalesced V^T store
    {
        const int b  = r0 >> 12;
        const int s0 = r0 & (SEQ - 1);
        const int h  = s0 >> 10;
        const size_t vtb = (size_t)(b * 4 + h) * (32 * SEQ);
        const int hl = tid >> 8;             // 0..1 (hi/lo plane)
        const int d  = (tid >> 3) & 31;      // head-dim
        const int j  = tid & 7;              // k-octet within 64
        short8 tmp;
#pragma unroll
        for (int i = 0; i < 8; ++i) {
            const int kl = j * 8 + i;        // 0..63
            tmp[i] = (short)vsh[hl][kl >> 2][(kl & 3) * 32 + d];
        }
        unsigned short* dst = (hl ? Vtlo : Vthi) + vtb + (size_t)d * SEQ
                            + (size_t)(s0 & 1023) * 4 + j * 8;
        *(short8*)dst = tmp;
    }
}

__global__ __launch_bounds__(512, 4) void qkv_kernel(
    const int* __restrict__ seq, const void* emb,
    const float* __restrict__ wt4, const float* __restrict__ pe,
    unsigned short* Qhi, unsigned short* Qlo,
    unsigned short* Khi, unsigned short* Klo,
    unsigned short* Vthi, unsigned short* Vtlo,
    const int* __restrict__ flag)
{
    if (*flag)
        qkv_body<float>(seq, (const float*)emb, wt4, pe,
                        Qhi, Qlo, Khi, Klo, Vthi, Vtlo);
    else
        qkv_body<__hip_bfloat16>(seq, (const __hip_bfloat16*)emb, wt4, pe,
                                 Qhi, Qlo, Khi, Klo, Vthi, Vtlo);
}

// ---------------------------------------------------------------------------
// Kernel 2 (R30): flash attention = R29 (verified 50.9us) + bf16 P-buffer.
//   P stored in LDS as ushort bf16 (rne applied at WRITE; MFMA consumes
//   identical values, l still accumulates f32 -> bit-identical). pb16 row
//   stride 40 shorts (80B): 16B-aligned short8 reads, benign conflicts.
//   LDS 33792 -> 29696 B (<32KB) so FIVE blocks/CU (20 waves/CU, was 16).
// ---------------------------------------------------------------------------
__global__ __launch_bounds__(256, 5) void attn_kernel(
    const unsigned short* __restrict__ Qhi, const unsigned short* __restrict__ Qlo,
    const unsigned short* __restrict__ Khi, const unsigned short* __restrict__ Klo,
    const unsigned short* __restrict__ Vthi, const unsigned short* __restrict__ Vtlo,
    float* __restrict__ Apart, float* __restrict__ lbuf)
{
    const int bh   = blockIdx.x;
    const int pair = blockIdx.y;                  // 0..31
    const int kh   = blockIdx.z;                  // 0..3
    const size_t baseQ  = (size_t)(bh >> 2) * SEQ * D_MODEL + (size_t)(bh & 3) * SEQ * HEAD_DIM;
    const size_t baseVt = (size_t)bh * (32 * SEQ);

    const int tid  = threadIdx.x;
    const int wid  = __builtin_amdgcn_readfirstlane(tid >> 6);
    const int lane = tid & 63;
    const int rt   = wid;                         // 0..3
    const int quad = lane >> 4;
    const int col  = lane & 15;

    __shared__ __align__(16) unsigned short pbuf[4][16 * 40];   // 5120 B
    __shared__ __align__(16) unsigned char kv[3][8192];         // 24576 B
    unsigned short* pb16 = pbuf[wid];

    // stage one chunk's plane for this wave: 2 x (16B/lane) async copies
    const int r4 = lane >> 2, sseg = lane & 3;
    auto stage = [&](int bufi, int kbase) {
#pragma unroll
        for (int half = 0; half < 2; ++half) {
            const int row = half * 16 + r4;
            const int seg = sseg ^ (row & 3);     // pre-swizzled source (rule #21)
            const unsigned short* src;
            if (wid == 0)      src = Khi  + baseQ  + (size_t)(kbase + row) * HEAD_DIM + seg * 8;
            else if (wid == 1) src = Klo  + baseQ  + (size_t)(kbase + row) * HEAD_DIM + seg * 8;
            else if (wid == 2) src = Vthi + baseVt + (size_t)row * SEQ + kbase + seg * 8;
            else               src = Vtlo + baseVt + (size_t)row * SEQ + kbase + seg * 8;
            g2l16(src, &kv[bufi][wid * 2048 + half * 1024]);
        }
    };
    // swizzled fragment read: plane 0..3, row 0..31, quad 0..3 (16B)
    auto frag = [&](int bufi, int plane, int row) -> short8 {
        const int byte = plane * 2048 + row * 64 + ((quad ^ (row & 3)) << 4);
        return *(const short8*)(&kv[bufi][byte]);
    };

#pragma unroll 1
    for (int ti = 0; ti < 2; ++ti) {
        const int qt = ti ? (63 - pair) : pair;
        const int qrow0 = qt * 64 + rt * 16;

        short8 qhiF, qloF;
        {
            const size_t qo = baseQ + (size_t)(qrow0 + col) * HEAD_DIM + quad * 8;
            qhiF = *(const short8*)(Qhi + qo);
            qloF = *(const short8*)(Qlo + qo);
        }

        f32x4 O0 = {0.f, 0.f, 0.f, 0.f};
        f32x4 O1 = {0.f, 0.f, 0.f, 0.f};
        float l[4] = {0.f, 0.f, 0.f, 0.f};

        const int N   = 2 * (qt + 1);
        const int nb  = N >> 2, rem = N & 3;
        const int cnt  = nb + ((kh < rem) ? 1 : 0);     // block-uniform
        const int cbeg = kh * nb + ((kh < rem) ? kh : rem);

        if (cnt > 0) {
            stage(0, cbeg * 32);
            if (cnt > 1) stage(1, (cbeg + 1) * 32);
            int cur = 0;
            for (int i = 0; i < cnt; ++i) {
                const int c = cbeg + i;
                const int kbase = c * 32;
                if (i + 1 < cnt) { asm volatile("s_waitcnt vmcnt(2)" ::: "memory"); }
                else             { asm volatile("s_waitcnt vmcnt(0)" ::: "memory"); }
                __builtin_amdgcn_s_barrier();         // all 4 planes of buf[cur] ready
                __builtin_amdgcn_sched_barrier(0);    // pin restage below the barrier
                if (i + 2 < cnt) {
                    int nx = cur + 2; if (nx > 2) nx -= 3;
                    stage(nx, (c + 2) * 32);          // (i+2)%3 == (i-1)%3: safe post-barrier
                }

                const short8 k0h = frag(cur, 0, col);
                const short8 k0l = frag(cur, 1, col);
                const short8 k1h = frag(cur, 0, col + 16);
                const short8 k1l = frag(cur, 1, col + 16);

                f32x4 s0v = {0.f, 0.f, 0.f, 0.f};
                f32x4 s1v = {0.f, 0.f, 0.f, 0.f};
                s0v = __builtin_amdgcn_mfma_f32_16x16x32_bf16(qhiF, k0h, s0v, 0, 0, 0);
                s0v = __builtin_amdgcn_mfma_f32_16x16x32_bf16(qhiF, k0l, s0v, 0, 0, 0);
                s0v = __builtin_amdgcn_mfma_f32_16x16x32_bf16(qloF, k0h, s0v, 0, 0, 0);
                s1v = __builtin_amdgcn_mfma_f32_16x16x32_bf16(qhiF, k1h, s1v, 0, 0, 0);
                s1v = __builtin_amdgcn_mfma_f32_16x16x32_bf16(qhiF, k1l, s1v, 0, 0, 0);
                s1v = __builtin_amdgcn_mfma_f32_16x16x32_bf16(qloF, k1h, s1v, 0, 0, 0);

                // fixed m=0 softmax numerator: e = exp(|s|) where unmasked, else 0
                // rne->bf16 applied at WRITE (same values reach the MFMA)
#pragma unroll
                for (int r = 0; r < 4; ++r) {
                    const int rowg = qrow0 + quad * 4 + r;
                    const float e0 = (kbase + col      <= rowg) ? __expf(fabsf(s0v[r])) : 0.f;
                    const float e1 = (kbase + 16 + col <= rowg) ? __expf(fabsf(s1v[r])) : 0.f;
                    l[r] += e0 + e1;
                    pb16[(quad * 4 + r) * 40 + col]      = rne_bf16(e0);
                    pb16[(quad * 4 + r) * 40 + 16 + col] = rne_bf16(e1);
                }
                const short8 ph = *(const short8*)&pb16[col * 40 + quad * 8];

                const short8 v0h = frag(cur, 2, col);
                const short8 v0l = frag(cur, 3, col);
                const short8 v1h = frag(cur, 2, col + 16);
                const short8 v1l = frag(cur, 3, col + 16);

                O0 = __builtin_amdgcn_mfma_f32_16x16x32_bf16(ph, v0h, O0, 0, 0, 0);
                O0 = __builtin_amdgcn_mfma_f32_16x16x32_bf16(ph, v0l, O0, 0, 0, 0);
                O1 = __builtin_amdgcn_mfma_f32_16x16x32_bf16(ph, v1h, O1, 0, 0, 0);
                O1 = __builtin_amdgcn_mfma_f32_16x16x32_bf16(ph, v1l, O1, 0, 0, 0);

                cur = (cur == 2) ? 0 : cur + 1;
            }
        }

        // row-sum of l across the 16 cols
#pragma unroll
        for (int off = 1; off < 16; off <<= 1) {
#pragma unroll
            for (int r = 0; r < 4; ++r) l[r] += __shfl_xor(l[r], off, 64);
        }

        // direct partial writes -- no cross-wave combine
        float* Ap = Apart + (size_t)kh * (BATCH * SEQ * D_MODEL) + baseQ;
#pragma unroll
        for (int r = 0; r < 4; ++r) {
            const int row = qrow0 + quad * 4 + r;
            Ap[(size_t)row * HEAD_DIM + col]      = O0[r];
            Ap[(size_t)row * HEAD_DIM + 16 + col] = O1[r];
        }
        if (col == 0) {
            float* lp = lbuf + ((size_t)kh * (BATCH * NUM_HEAD) + bh) * SEQ;
#pragma unroll
            for (int r = 0; r < 4; ++r)
                lp[qrow0 + quad * 4 + r] = l[r];
        }

        __builtin_amdgcn_s_barrier();   // all waves done reading kv before next-ti restage
    }
}

// ---------------------------------------------------------------------------
// Kernel 3: out = att @ Wo^T, 4-way kh partial sum + 1/L folded in (unchanged)
// ---------------------------------------------------------------------------
template <typename T>
__device__ __forceinline__ void out_proj_body(
    const float* __restrict__ Apart, const float* __restrict__ lbuf,
    const float* __restrict__ wo4t, T* __restrict__ out)
{
    const int tid = threadIdx.x;
    const int e   = tid & 127;
    const int grp = tid >> 7;                 // 0..1 -> rows grp*4 .. grp*4+3
    const int r0  = blockIdx.x * RROWS;

    __shared__ __align__(16) float xs[RROWS][D_MODEL];
#pragma unroll
    for (int k = 0; k < 4; ++k) {
        const int idx = k * 256 + tid;        // 0..1023
        const int rr = idx >> 7;
        const int ee = idx & 127;
        const int gr = r0 + rr;               // global token row
        const int b  = gr >> 12;
        const int s  = gr & (SEQ - 1);
        const int bh = b * 4 + (s >> 10);
        const int hr = ((s & 1023) << 2) + (ee >> 5);   // head-row
        const size_t ai = (size_t)gr * D_MODEL + ee;
        float sum = 0.f, Ls = 0.f;
#pragma unroll
        for (int kh = 0; kh < 4; ++kh) {
            sum += Apart[(size_t)kh * (BATCH * SEQ * D_MODEL) + ai];
            Ls  += lbuf[((size_t)kh * (BATCH * NUM_HEAD) + bh) * SEQ + hr];
        }
        xs[rr][ee] = sum * (1.f / Ls);
    }
    __syncthreads();

    float acc[4] = {0.f, 0.f, 0.f, 0.f};
    const int rbase = grp * 4;
    const float4* w4 = (const float4*)wo4t;

    for (int dq = 0; dq < 32; ++dq) {
        float4 xr[4];
#pragma unroll
        for (int r = 0; r < 4; ++r) xr[r] = *(const float4*)&xs[rbase + r][dq * 4];
        const float4 w_ = w4[dq * 128 + e];
#pragma unroll
        for (int r = 0; r < 4; ++r) {
            acc[r] += xr[r].x * w_.x; acc[r] += xr[r].y * w_.y;
            acc[r] += xr[r].z * w_.z; acc[r] += xr[r].w * w_.w;
        }
    }
#pragma unroll
    for (int r = 0; r < 4; ++r)
        storef(out, (size_t)(r0 + rbase + r) * D_MODEL + e, acc[r]);
}

__global__ __launch_bounds__(256, 4) void out_proj_kernel(
    const float* __restrict__ Apart, const float* __restrict__ lbuf,
    const float* __restrict__ wo4t, void* out,
    const int* __restrict__ flag)
{
    if (*flag)
        out_proj_body<float>(Apart, lbuf, wo4t, (float*)out);
    else
        out_proj_body<__hip_bfloat16>(Apart, lbuf, wo4t, (__hip_bfloat16*)out);
}

extern "C" void kernel_launch(void* const* d_in, const int* in_sizes, int n_in,
                              void* d_out, int out_size, void* d_ws, size_t ws_size,
                              hipStream_t stream) {
    const int* seq = (const int*)d_in[0];
    const void* emb = d_in[1];
    const void* wq  = d_in[2];
    const void* wk  = d_in[3];
    const void* wv  = d_in[4];
    const void* wo  = d_in[5];

    const size_t N = (size_t)BATCH * SEQ * D_MODEL;   // 1,048,576 elements
    int*            flag = (int*)d_ws;
    unsigned short* Qhi  = (unsigned short*)((char*)d_ws + 256);
    unsigned short* Qlo  = Qhi + N;
    unsigned short* Khi  = Qlo + N;
    unsigned short* Klo  = Khi + N;
    unsigned short* Vthi = Klo + N;
    unsigned short* Vtlo = Vthi + N;
    float*          Apart = (float*)(Vtlo + N);       // 4 x [B,S,128] f32 (16 MB)
    float*          lbuf  = Apart + 4 * N;            // 4 x 8 x 4096 f32 (512 KB)
    float*          wt4   = lbuf + 4 * BATCH * NUM_HEAD * SEQ;
    float*          pe    = wt4 + 65536;              // 4096 x 128 f32 PE table

    prep_kernel<<<dim3(64 + 8), dim3(256), 0, stream>>>(wq, wk, wv, wo, wt4, pe, flag);
    qkv_kernel<<<dim3(BATCH * SEQ / QROWS), dim3(512), 0, stream>>>(
        seq, emb, wt4, pe,
        Qhi, Qlo, Khi, Klo, Vthi, Vtlo, flag);
    attn_kernel<<<dim3(BATCH * NUM_HEAD, 32, 4), dim3(256), 0, stream>>>(
        Qhi, Qlo, Khi, Klo, Vthi, Vtlo, Apart, lbuf);
    out_proj_kernel<<<dim3(BATCH * SEQ / RROWS), dim3(256), 0, stream>>>(
        Apart, lbuf, wt4 + 49152, d_out, flag);
}